// Round 7
// baseline (113.188 us; speedup 1.0000x reference)
//
#include <hip/hip_runtime.h>

#define Tcnt 32768      // B*S
#define Gn   2
#define Vn   320
#define Dn   128
#define DIMK 512
#define GV   640        // G*V
#define RB   64         // rows per fused block

typedef __attribute__((ext_vector_type(8))) short bf16x8;
typedef __attribute__((ext_vector_type(4))) ushort u16x4;
typedef __attribute__((ext_vector_type(4))) float f32x4;

__device__ inline ushort f2bf(float x) {
    unsigned u = __float_as_uint(x);
    return (ushort)((u + 0x7fffu + ((u >> 16) & 1u)) >> 16);   // RNE
}

#define AS1(p) ((const __attribute__((address_space(1))) void*)(p))
#define AS3(p) ((__attribute__((address_space(3))) void*)(p))

// ---------------- prep: W [512,640] fp32 -> Wt [640,512] bf16 (transposed) ----------
__global__ __launch_bounds__(256) void prep_wt(
    const float* __restrict__ W, ushort* __restrict__ Wt)
{
    __shared__ ushort Ls[64][72];
    int t = blockIdx.x;                     // 0..79
    int n0 = (t % 10) * 64, k0 = (t / 10) * 64;
    int ln = threadIdx.x & 63, kq = threadIdx.x >> 6;
    #pragma unroll
    for (int kk = 0; kk < 16; ++kk) {
        int k = kq * 16 + kk;
        Ls[k][ln] = f2bf(W[(size_t)(k0 + k) * GV + n0 + ln]);
    }
    __syncthreads();
    #pragma unroll
    for (int nn = 0; nn < 16; ++nn) {
        int n = kq * 16 + nn;
        Wt[(size_t)(n0 + n) * DIMK + k0 + ln] = Ls[ln][n];
    }
}

// ------- fused: GEMM(64x320) + bias + softmax + gumbel-argmax(+fixup) + gather ------
__global__ __launch_bounds__(512, 4) void fused_vq_kernel(
    const float*  __restrict__ hs,    // [T, 512] fp32
    const ushort* __restrict__ Wt,    // [640, 512] bf16 transposed
    const float*  __restrict__ W,     // [512, 640] fp32 (fixup only)
    const float*  __restrict__ bias,  // [640]
    const float*  __restrict__ gum,   // [T*G, 320]
    const float*  __restrict__ cv,    // [640, 128]
    float* __restrict__ out,          // [T, 256]
    float* __restrict__ dist)         // [T*G, 320]
{
    __shared__ union SMem {
        struct { ushort As[2][RB * 32]; ushort Bs[2][Vn * 32]; } gm;  // 8 + 40 KB
        float Ls[32][324];                                            // 41.5 KB
    } U;
    __shared__ int    s_cnt[RB];
    __shared__ int    s_col[RB][8];
    __shared__ float  s_gm[RB][8];
    __shared__ int    s_bidx[RB];

    const int tid = threadIdx.x, w = tid >> 6, lane = tid & 63;
    const int Q = lane >> 4, c16 = lane & 15;
    const int wm = (w >> 1) * 16, wn = (w & 1) * 160;

    const int bid = blockIdx.x;
    const int swz = (bid & 7) * 128 + (bid >> 3);   // XCD chunking (1024 % 8 == 0)
    const int g = swz & 1;                          // (t,g0),(t,g1) adjacent on same XCD
    const size_t t0 = (size_t)(swz >> 1) * RB;

    if (tid < RB) s_cnt[tid] = 0;

    // ---- A staging map: thread -> (row, phys 4-float chunk); source pre-swizzled ----
    const int arow_s = tid >> 3, pc = tid & 7;
    const int lq = (pc >> 1) ^ ((arow_s >> 1) & 3);
    const int lc = lq * 2 + (pc & 1);
    const float* asrc = hs + (t0 + arow_s) * DIMK + lc * 4;
    const ushort* wtg = Wt + (size_t)g * Vn * DIMK;

    auto stageB = [&](int buf, int k0) {
        #pragma unroll
        for (int i2 = 0; i2 < 2; ++i2) {
            int s = i2 * 512 + tid;
            int n = s >> 2, pq = s & 3, lqq = pq ^ ((n >> 1) & 3);
            __builtin_amdgcn_global_load_lds(
                AS1(wtg + (size_t)n * DIMK + k0 + lqq * 8),
                AS3(&U.gm.Bs[buf][s * 8]), 16, 0, 0);
        }
        if (w < 4) {
            int s = 1024 + tid;
            int n = s >> 2, pq = s & 3, lqq = pq ^ ((n >> 1) & 3);
            __builtin_amdgcn_global_load_lds(
                AS1(wtg + (size_t)n * DIMK + k0 + lqq * 8),
                AS3(&U.gm.Bs[buf][s * 8]), 16, 0, 0);
        }
    };
    auto writeA = [&](int buf, float4 v) {
        u16x4 o;
        o[0] = f2bf(v.x); o[1] = f2bf(v.y); o[2] = f2bf(v.z); o[3] = f2bf(v.w);
        *(u16x4*)&U.gm.As[buf][tid * 4] = o;
    };

    // ---- prologue: stage step 0, prefetch step 1 into regs ----
    float4 areg0 = *(const float4*)(asrc);
    stageB(0, 0);
    float4 areg1 = *(const float4*)(asrc + 32);
    writeA(0, areg0);
    __syncthreads();

    f32x4 acc[10];
    #pragma unroll
    for (int j = 0; j < 10; ++j) acc[j] = (f32x4){0.f, 0.f, 0.f, 0.f};

    // ---- K loop: 16 steps BK=32, dbuf B (gll), depth-2 A reg prefetch ----
    #pragma unroll
    for (int ks = 0; ks < 16; ++ks) {
        if (ks + 2 < 16) {
            if ((ks & 1) == 0) areg0 = *(const float4*)(asrc + (ks + 2) * 32);
            else               areg1 = *(const float4*)(asrc + (ks + 2) * 32);
        }
        if (ks + 1 < 16) stageB((ks + 1) & 1, (ks + 1) * 32);

        const ushort* Ab = U.gm.As[ks & 1];
        const ushort* Bb = U.gm.Bs[ks & 1];
        const int ar = wm + c16;
        bf16x8 af = *(const bf16x8*)&Ab[(ar * 4 + (Q ^ ((ar >> 1) & 3))) * 8];
        #pragma unroll
        for (int j = 0; j < 10; ++j) {
            int n = wn + j * 16 + c16;
            bf16x8 bv = *(const bf16x8*)&Bb[(n * 4 + (Q ^ ((n >> 1) & 3))) * 8];
            acc[j] = __builtin_amdgcn_mfma_f32_16x16x32_bf16(af, bv, acc[j], 0, 0, 0);
        }
        if (ks + 1 < 16) writeA((ks + 1) & 1, ((ks + 1) & 1) ? areg1 : areg0);
        __syncthreads();
    }

    // ---- bias ----
    #pragma unroll
    for (int j = 0; j < 10; ++j) {
        float bb = bias[g * Vn + wn + j * 16 + c16];
        acc[j][0] += bb; acc[j][1] += bb; acc[j][2] += bb; acc[j][3] += bb;
    }

    const float MARGIN = 0.0625f;

    // ==== epilogue: two row-group passes through LDS transpose ====
    #pragma unroll
    for (int grp = 0; grp < 2; ++grp) {
        __syncthreads();             // previous pass fully read / GEMM LDS free
        if ((w >> 2) == grp) {
            // this wave's rows belong to the group: write acc -> Ls
            #pragma unroll
            for (int qr = 0; qr < 4; ++qr) {
                int lrow = (wm - grp * 32) + Q * 4 + qr;   // 0..31 (C/D layout row)
                #pragma unroll
                for (int j = 0; j < 10; ++j)
                    U.Ls[lrow][wn + j * 16 + c16] = acc[j][qr];
            }
        }
        __syncthreads();
        // all 8 waves process 4 full rows each
        for (int ri = 0; ri < 4; ++ri) {
            int rl = w * 4 + ri;                 // 0..31
            int row = grp * 32 + rl;             // 0..63
            size_t r2 = (t0 + row) * 2 + g;
            const float* gr = gum + r2 * Vn;
            float lg[5], sv[5];
            #pragma unroll
            for (int j = 0; j < 5; ++j) {
                lg[j] = U.Ls[rl][lane + j * 64];
                sv[j] = lg[j] + gr[lane + j * 64];
            }
            float mxl = -1e30f, mxs = -1e30f; int bi = 0;
            #pragma unroll
            for (int j = 0; j < 5; ++j) {
                mxl = fmaxf(mxl, lg[j]);
                if (sv[j] > mxs) { mxs = sv[j]; bi = lane + j * 64; }
            }
            #pragma unroll
            for (int off = 1; off < 64; off <<= 1) {
                mxl = fmaxf(mxl, __shfl_xor(mxl, off));
                float os = __shfl_xor(mxs, off); int ob = __shfl_xor(bi, off);
                if (os > mxs || (os == mxs && ob < bi)) { mxs = os; bi = ob; }
            }
            float ev[5]; float sum = 0.f;
            #pragma unroll
            for (int j = 0; j < 5; ++j) { ev[j] = __expf(lg[j] - mxl); sum += ev[j]; }
            #pragma unroll
            for (int off = 1; off < 64; off <<= 1) sum += __shfl_xor(sum, off);
            float inv = 1.0f / sum;
            float* dr = dist + r2 * Vn;
            #pragma unroll
            for (int j = 0; j < 5; ++j) dr[lane + j * 64] = ev[j] * inv;

            if (lane == 0) s_bidx[row] = bi;
            // near-tie candidates (exact threshold, full-row max known)
            float thr = mxs - MARGIN;
            int tot = 0;
            #pragma unroll
            for (int j = 0; j < 5; ++j)
                tot += __popcll(__ballot(sv[j] >= thr));
            if (tot > 1) {
                #pragma unroll
                for (int j = 0; j < 5; ++j) {
                    if (sv[j] >= thr) {
                        int pos = atomicAdd(&s_cnt[row], 1);
                        if (pos < 8) {
                            s_col[row][pos] = lane + j * 64;
                            s_gm[row][pos]  = sv[j] - lg[j];
                        }
                    }
                }
            }
        }
    }
    __syncthreads();

    // ---- fixup: exact fp32 recompute for near-tie rows (8 units/wave) ----
    for (int ui = 0; ui < 8; ++ui) {
        int u = w * 8 + ui;
        int c = s_cnt[u];
        if (c > 1) {
            if (c > 8) c = 8;
            size_t t = t0 + u;
            const float* hr = hs + t * DIMK;
            float4 h0 = *(const float4*)(hr + lane * 8);
            float4 h1 = *(const float4*)(hr + lane * 8 + 4);
            float hv[8] = {h0.x, h0.y, h0.z, h0.w, h1.x, h1.y, h1.z, h1.w};
            float best = -1e30f; int bv2 = 1 << 30;
            for (int j = 0; j < c; ++j) {
                int v = s_col[u][j];
                int gcol = g * Vn + v;
                const float* wc = W + gcol;
                float p = 0.f;
                #pragma unroll
                for (int i = 0; i < 8; ++i)
                    p = fmaf(hv[i], wc[(size_t)(lane * 8 + i) * GV], p);
                #pragma unroll
                for (int off = 1; off < 64; off <<= 1) p += __shfl_xor(p, off);
                float se = p + bias[gcol] + s_gm[u][j];
                if (se > best || (se == best && v < bv2)) { best = se; bv2 = v; }
            }
            if (lane == 0) s_bidx[u] = bv2;
        }
    }
    __syncthreads();

    // ---- gather codevectors -> out ----
    for (int ui = 0; ui < 8; ++ui) {
        int u = w * 8 + ui;
        size_t t = t0 + u;
        int b = s_bidx[u];
        const float2* cvr = (const float2*)(cv + ((size_t)(g * Vn + b)) * Dn);
        float2 val = cvr[lane];
        *(float2*)(out + t * (Gn * Dn) + g * Dn + lane * 2) = val;
    }
}

extern "C" void kernel_launch(void* const* d_in, const int* in_sizes, int n_in,
                              void* d_out, int out_size, void* d_ws, size_t ws_size,
                              hipStream_t stream) {
    const float* hs  = (const float*)d_in[0];  // [8,4096,512]
    const float* W   = (const float*)d_in[1];  // [512,640]
    const float* b   = (const float*)d_in[2];  // [640]
    const float* cv  = (const float*)d_in[3];  // [640,128]
    const float* gum = (const float*)d_in[4];  // [65536,320]

    float* out  = (float*)d_out;                      // [32768, 256]
    float* dist = out + (size_t)Tcnt * (Gn * Dn);     // [65536, 320]
    ushort* Wt  = (ushort*)d_ws;                      // [640, 512] bf16 = 640 KB

    prep_wt<<<80, 256, 0, stream>>>(W, Wt);
    fused_vq_kernel<<<(Tcnt / RB) * Gn, 512, 0, stream>>>(hs, Wt, W, b, gum, cv, out, dist);
}